// Round 3
// baseline (106.766 us; speedup 1.0000x reference)
//
#include <hip/hip_runtime.h>
#include <math.h>

// Problem constants (from reference: N=512, D=4096, fp32).
#define PN 512
#define PD 4096

// Fused single-pass-K GEMM: 32x16 C-tile, grid 512 (2 blocks/CU), K staged in
// BK chunks, triple-buffered LDS, counted-vmcnt pipeline (T3/T4), depth 2.
#define BK 256
#define NST (PD / BK)  // 16 stages

// ws layout (bytes):
//   [0,2048)    sa (512 f32)        float idx 0
//   [2048,4096) sp                  float idx 512
//   [4096,6144) dd (diag dist)      float idx 1024
//   [6144]      sum (f32 atomic)    float idx 1536
//   [6148]      cnt (u32 atomic)    idx 1537
//   [6152]      done (u32 ticket)   idx 1538
//   [8192, +4MB)        ah bf16 [512][4096]
//   [8192+4MB, +8MB)    ph bf16 [512][4096]
#define WS_AH_BYTES 8192
#define WS_PH_BYTES (8192 + 4194304)
#define WS_NEED_MAIN ((size_t)(8192 + 2 * 4194304))

typedef __attribute__((ext_vector_type(8))) short short8;
typedef __attribute__((ext_vector_type(4))) float floatx4;

static __device__ __forceinline__ unsigned short f2bf(float x) {
    // round-to-nearest-even fp32 -> bf16 (inputs are finite normals)
    unsigned int u = __float_as_uint(x);
    u += 0x7fffu + ((u >> 16) & 1u);
    return (unsigned short)(u >> 16);
}

static __device__ __forceinline__ void load16_lds(const void* gp, void* lp) {
    // 16B per lane, LDS dest = wave-uniform base + lane*16
    __builtin_amdgcn_global_load_lds(
        (const __attribute__((address_space(1))) unsigned int*)gp,
        (__attribute__((address_space(3))) unsigned int*)lp,
        16, 0, 0);
}

struct ushort4s { unsigned short x, y, z, w; };

// ---------------- prep: norms + diag dist + fp32->bf16 conversion ----------------
__global__ __launch_bounds__(256) void taw_prep_kernel(
        const float* __restrict__ a, const float* __restrict__ p,
        float* __restrict__ ws, int conv) {
    const int i = blockIdx.x;
    const int t = threadIdx.x;
    if (i == 0 && t == 0) {
        ws[1536] = 0.0f;
        ((unsigned int*)ws)[1537] = 0u;
        ((unsigned int*)ws)[1538] = 0u;
    }
    const float4* a4 = (const float4*)(a + (size_t)i * PD);
    const float4* p4 = (const float4*)(p + (size_t)i * PD);
    unsigned short* ah = (unsigned short*)((char*)ws + WS_AH_BYTES) + (size_t)i * PD;
    unsigned short* ph = (unsigned short*)((char*)ws + WS_PH_BYTES) + (size_t)i * PD;
    float sa = 0.f, sp = 0.f, dp = 0.f;
#pragma unroll
    for (int c = 0; c < 4; ++c) {
        const int e = c * 256 + t;      // float4 index
        float4 av = a4[e];
        float4 pv = p4[e];
        sa += av.x * av.x + av.y * av.y + av.z * av.z + av.w * av.w;
        sp += pv.x * pv.x + pv.y * pv.y + pv.z * pv.z + pv.w * pv.w;
        dp += av.x * pv.x + av.y * pv.y + av.z * pv.z + av.w * pv.w;
        if (conv) {
            ushort4s ab = {f2bf(av.x), f2bf(av.y), f2bf(av.z), f2bf(av.w)};
            ushort4s pb = {f2bf(pv.x), f2bf(pv.y), f2bf(pv.z), f2bf(pv.w)};
            *(ushort4s*)(ah + (size_t)e * 4) = ab;
            *(ushort4s*)(ph + (size_t)e * 4) = pb;
        }
    }
#pragma unroll
    for (int off = 32; off > 0; off >>= 1) {
        sa += __shfl_down(sa, off, 64);
        sp += __shfl_down(sp, off, 64);
        dp += __shfl_down(dp, off, 64);
    }
    __shared__ float red[3][4];
    const int wave = t >> 6;
    if ((t & 63) == 0) { red[0][wave] = sa; red[1][wave] = sp; red[2][wave] = dp; }
    __syncthreads();
    if (t == 0) {
        sa = red[0][0] + red[0][1] + red[0][2] + red[0][3];
        sp = red[1][0] + red[1][1] + red[1][2] + red[1][3];
        dp = red[2][0] + red[2][1] + red[2][2] + red[2][3];
        float d2 = sa - 2.f * dp + sp;
        d2 = fmaxf(d2, 0.f);
        ws[i] = sa;
        ws[512 + i] = sp;
        ws[1024 + i] = (d2 == 0.f) ? 0.f : sqrtf(d2);
    }
}

// ---------------- fused single-pass GEMM + epilogue + finalize ----------------
// grid 512 blocks = 16(i) x 32(j) tile grid, tile 32x16, 256 threads = 4 waves.
// 2 blocks/CU (72 KB LDS) -> 8 waves/CU of cross-block TLP.
// K split ACROSS waves: wave w computes the FULL 32x16 tile over k-chunks
// {2w, 2w+1} of each BK=256 slab; partial accumulators reduced via LDS.
// LDS fragment order: lds[buf][24 groups][64 lanes][8 bf16].
//   A groups G=0..15: lane l holds row (G&1)*16+(l&15), k=(G>>1)*32+(l>>4)*8
//   P groups G=16..23 (g=G-16): lane l holds row (l&15), k=g*32+(l>>4)*8
// Pipeline: triple buffer, prefetch depth 2, counted s_waitcnt vmcnt(12)
// (6 global_load_lds per wave per stage; 2 stages stay in flight).
__global__ __launch_bounds__(256) void taw_fused_kernel(
        float* __restrict__ ws, float* __restrict__ out) {
    __shared__ short lds[3][24][64][8];  // 72 KB triple buffer
    const unsigned short* ah = (const unsigned short*)((const char*)ws + WS_AH_BYTES);
    const unsigned short* ph = (const unsigned short*)((const char*)ws + WS_PH_BYTES);
    const int t = threadIdx.x;
    const int lane = t & 63;
    const int w = t >> 6;

    // XCD-chunked swizzle: linear block B maps to XCD B&7 (heuristic). Each
    // XCD gets a 4(i) x 16(j) chunk of the 16x32 tile grid -> per-XCD working
    // set (128 a-rows + 256 p-rows = 3 MB bf16) fits its 4 MB L2.
    const int B = blockIdx.x;
    const int xcd = B & 7;
    const int l = B >> 3;                           // 0..63 within XCD
    const int bi = ((xcd >> 1) << 2) + (l >> 4);    // 0..15
    const int bj = ((xcd & 1) << 4) + (l & 15);     // 0..31
    const int i0 = bi * 32;
    const int j0 = bj * 16;

    // Staging: wave w stages groups w*6..w*6+5 (6 x global_load_lds / stage).
    const unsigned short* sbase[6];
#pragma unroll
    for (int q = 0; q < 6; ++q) {
        const int G = w * 6 + q;  // wave-uniform
        const unsigned short* bp;
        int row, kk;
        if (G < 16) {            // A-tile group
            row = i0 + ((G & 1) << 4) + (lane & 15);
            kk = ((G >> 1) << 5) + ((lane >> 4) << 3);
            bp = ah;
        } else {                 // P-tile group
            const int g = G - 16;
            row = j0 + (lane & 15);
            kk = (g << 5) + ((lane >> 4) << 3);
            bp = ph;
        }
        sbase[q] = bp + (size_t)row * PD + kk;
    }

    auto STAGE = [&](int buf, int kst) {
#pragma unroll
        for (int q = 0; q < 6; ++q) {
            load16_lds(sbase[q] + kst, &lds[buf][w * 6 + q][0][0]);
        }
    };

    floatx4 acc[2];
    acc[0] = (floatx4){0.f, 0.f, 0.f, 0.f};
    acc[1] = (floatx4){0.f, 0.f, 0.f, 0.f};

    STAGE(0, 0);
    STAGE(1, BK);
    for (int st = 0; st < NST; ++st) {
        const int b = st - (st / 3) * 3;  // st % 3
        if (st + 2 < NST) {
            STAGE(st + 2 - ((st + 2) / 3) * 3, (st + 2) * BK);
            // stages st+1, st+2 (12 loads/wave) stay in flight; stage st landed
            asm volatile("s_waitcnt vmcnt(12)" ::: "memory");
        } else if (st + 1 < NST) {
            asm volatile("s_waitcnt vmcnt(6)" ::: "memory");
        } else {
            asm volatile("s_waitcnt vmcnt(0)" ::: "memory");
        }
        __builtin_amdgcn_s_barrier();       // all waves' stage-st loads landed
        __builtin_amdgcn_sched_barrier(0);  // pin ds_reads below the barrier
#pragma unroll
        for (int c = 0; c < 2; ++c) {
            const int kb = 2 * w + c;       // wave-private k-chunks
            short8 a0 = *(const short8*)&lds[b][2 * kb + 0][lane][0];
            short8 a1 = *(const short8*)&lds[b][2 * kb + 1][lane][0];
            short8 p0 = *(const short8*)&lds[b][16 + kb][lane][0];
            acc[0] = __builtin_amdgcn_mfma_f32_16x16x32_bf16(a0, p0, acc[0], 0, 0, 0);
            acc[1] = __builtin_amdgcn_mfma_f32_16x16x32_bf16(a1, p0, acc[1], 0, 0, 0);
        }
        __builtin_amdgcn_sched_barrier(0);  // pin compute above the drain
        asm volatile("s_waitcnt lgkmcnt(0)" ::: "memory");  // my ds_reads done
        __builtin_amdgcn_s_barrier();       // everyone's reads done -> next STAGE safe
    }

    // Cross-wave K-reduction of partial accumulators through LDS (8 KB).
    float* sc = (float*)&lds[0][0][0][0];
#pragma unroll
    for (int rm = 0; rm < 2; ++rm)
#pragma unroll
        for (int r = 0; r < 4; ++r)
            sc[((w * 2 + rm) * 4 + r) * 64 + lane] = acc[rm][r];
    __syncthreads();

    // Waves 0,1 finish m-fragment rm = w (tile is 32x16 = 2 fragments).
    // C/D layout: col=lane&15, row=(lane>>4)*4+r [m89-verified]
    float lsum = 0.f;
    unsigned int lcnt = 0;
    if (w < 2) {
        const int rm = w;
        const int jj = j0 + (lane & 15);
        const int ib = i0 + rm * 16 + ((lane >> 4) << 2);
        const float spv = ws[512 + jj];
#pragma unroll
        for (int r = 0; r < 4; ++r) {
            const float dot = sc[((0 * 2 + rm) * 4 + r) * 64 + lane]
                            + sc[((1 * 2 + rm) * 4 + r) * 64 + lane]
                            + sc[((2 * 2 + rm) * 4 + r) * 64 + lane]
                            + sc[((3 * 2 + rm) * 4 + r) * 64 + lane];
            const int ii = ib + r;
            float d2 = ws[ii] - 2.f * dot + spv;
            d2 = fmaxf(d2, 0.f);
            const float dist = (d2 == 0.f) ? 0.f : sqrtf(d2);
            const float v = (ii != jj) ? fmaxf(ws[1024 + ii] - dist, 0.f) : 0.f;
            lsum += v;
            lcnt += (v > 1e-16f) ? 1u : 0u;
        }
#pragma unroll
        for (int off = 32; off > 0; off >>= 1) {
            lsum += __shfl_down(lsum, off, 64);
            lcnt += __shfl_down(lcnt, off, 64);
        }
    }
    float* rs = sc + 2048;                       // carved block-reduce scratch
    unsigned int* rc = (unsigned int*)(sc + 2052);
    if (w < 2 && lane == 0) { rs[w] = lsum; rc[w] = lcnt; }
    __syncthreads();
    if (t == 0) {
        atomicAdd(ws + 1536, rs[0] + rs[1]);
        atomicAdd(((unsigned int*)ws) + 1537, rc[0] + rc[1]);
        __threadfence();  // make this block's sums device-visible before ticket
        const unsigned int old = atomicAdd(((unsigned int*)ws) + 1538, 1u);
        if (old == 511u) {  // last block: all 512 blocks' atomics are visible
            const float s = atomicAdd(ws + 1536, 0.f);          // coherent read
            const unsigned int c = atomicAdd(((unsigned int*)ws) + 1537, 0u);
            out[0] = (float)((double)s / ((double)c + 1e-16));
        }
    }
}

// ---------------- finalize (fallback path only) ----------------
__global__ void taw_finalize_kernel(const float* __restrict__ ws,
                                    float* __restrict__ out) {
    const double s = (double)ws[1536];
    const double c = (double)(((const unsigned int*)ws)[1537]);
    out[0] = (float)(s / (c + 1e-16));
}

// ---------------- fallback single-pass fp32 GEMM (Round-0/1 proven path) ----------------
__global__ __launch_bounds__(256) void taw_gemm_loss_kernel(
        const float* __restrict__ A, const float* __restrict__ P,
        float* __restrict__ ws) {
    __shared__ float as[32][34];
    __shared__ float bs[32][34];
    const int tx = threadIdx.x;
    const int ty = threadIdx.y;
    const int t = ty * 16 + tx;
    const int i0 = blockIdx.y * 32;
    const int j0 = blockIdx.x * 32;
    const int sr = t >> 3;
    const int sk = (t & 7) * 4;
    const float* aptr = A + (size_t)(i0 + sr) * PD + sk;
    const float* pptr = P + (size_t)(j0 + sr) * PD + sk;
    float c00 = 0.f, c01 = 0.f, c10 = 0.f, c11 = 0.f;
    for (int k0 = 0; k0 < PD; k0 += 32) {
        float4 av = *(const float4*)(aptr + k0);
        float4 pv = *(const float4*)(pptr + k0);
        __syncthreads();
        as[sk + 0][sr] = av.x; as[sk + 1][sr] = av.y;
        as[sk + 2][sr] = av.z; as[sk + 3][sr] = av.w;
        bs[sk + 0][sr] = pv.x; bs[sk + 1][sr] = pv.y;
        bs[sk + 2][sr] = pv.z; bs[sk + 3][sr] = pv.w;
        __syncthreads();
#pragma unroll
        for (int kk = 0; kk < 32; ++kk) {
            const float2 a2 = *(const float2*)&as[kk][2 * ty];
            const float2 b2 = *(const float2*)&bs[kk][2 * tx];
            c00 = fmaf(a2.x, b2.x, c00);
            c01 = fmaf(a2.x, b2.y, c01);
            c10 = fmaf(a2.y, b2.x, c10);
            c11 = fmaf(a2.y, b2.y, c11);
        }
    }
    const float* sq_a = ws;
    const float* sq_p = ws + 512;
    const float* ddg  = ws + 1024;
    const int i = i0 + 2 * ty;
    const int j = j0 + 2 * tx;
    float cvals[2][2] = {{c00, c01}, {c10, c11}};
    float lsum = 0.f;
    unsigned int lcnt = 0;
#pragma unroll
    for (int dr = 0; dr < 2; ++dr)
#pragma unroll
        for (int dc = 0; dc < 2; ++dc) {
            const int ii = i + dr, jj = j + dc;
            float d2 = sq_a[ii] - 2.f * cvals[dr][dc] + sq_p[jj];
            d2 = fmaxf(d2, 0.f);
            const float dist = (d2 == 0.f) ? 0.f : sqrtf(d2);
            const float v = (ii != jj) ? fmaxf(ddg[ii] - dist, 0.f) : 0.f;
            lsum += v;
            lcnt += (v > 1e-16f) ? 1u : 0u;
        }
#pragma unroll
    for (int off = 32; off > 0; off >>= 1) {
        lsum += __shfl_down(lsum, off, 64);
        lcnt += __shfl_down(lcnt, off, 64);
    }
    __shared__ float rsum[4];
    __shared__ unsigned int rcnt[4];
    if ((t & 63) == 0) { rsum[t >> 6] = lsum; rcnt[t >> 6] = lcnt; }
    __syncthreads();
    if (t == 0) {
        atomicAdd(ws + 1536, rsum[0] + rsum[1] + rsum[2] + rsum[3]);
        atomicAdd(((unsigned int*)ws) + 1537, rcnt[0] + rcnt[1] + rcnt[2] + rcnt[3]);
    }
}

extern "C" void kernel_launch(void* const* d_in, const int* in_sizes, int n_in,
                              void* d_out, int out_size, void* d_ws, size_t ws_size,
                              hipStream_t stream) {
    (void)in_sizes; (void)n_in; (void)out_size;
    const float* a = (const float*)d_in[0];
    const float* p = (const float*)d_in[1];
    float* out = (float*)d_out;
    float* ws = (float*)d_ws;

    const int use_mfma = (ws_size >= WS_NEED_MAIN) ? 1 : 0;
    taw_prep_kernel<<<PN, 256, 0, stream>>>(a, p, ws, use_mfma);
    if (use_mfma) {
        taw_fused_kernel<<<512, 256, 0, stream>>>(ws, out);
    } else {
        taw_gemm_loss_kernel<<<dim3(16, 16), dim3(16, 16), 0, stream>>>(a, p, ws);
        taw_finalize_kernel<<<1, 1, 0, stream>>>(ws, out);
    }
}

// Round 4
// 92.273 us; speedup vs baseline: 1.1571x; 1.1571x over previous
//
#include <hip/hip_runtime.h>
#include <math.h>

// Problem constants (from reference: N=512, D=4096, fp32).
#define PN 512
#define PD 4096

// bf16 MFMA split-K config (champion geometry, R0-verified at 87.7us)
#define KSZ 8
#define KCHUNK (PD / KSZ)     // 512
#define BK 64                 // K per LDS stage
#define NSTAGE (KCHUNK / BK)  // 8

// ws layout (bytes):
//   [0,2048)    sa (512 f32)        float idx 0
//   [2048,4096) sp                  float idx 512
//   [4096,6144) dd (diag dist)      float idx 1024
//   [6144]      sum (f32 atomic)    float idx 1536
//   [6148]      cnt (u32 atomic)    idx 1537
//   [6152]      done (u32 ticket)   idx 1538
//   [8192, +4MB)        ah bf16 [512][4096]
//   [8192+4MB, +8MB)    ph bf16 [512][4096]
//   [8192+8MB, +8MB)    split-K partials f32 [KSZ][512][512]
#define WS_AH_BYTES 8192
#define WS_PH_BYTES (8192 + 4194304)
#define WS_PART_FLOAT 2099200                 // (8192 + 2*4194304)/4
#define WS_NEED_BF16 ((size_t)(8192 + 2 * 4194304 + (size_t)KSZ * PN * PN * 4))

typedef __attribute__((ext_vector_type(8))) short short8;
typedef __attribute__((ext_vector_type(4))) float floatx4;

static __device__ __forceinline__ unsigned short f2bf(float x) {
    // round-to-nearest-even fp32 -> bf16 (inputs are finite normals)
    unsigned int u = __float_as_uint(x);
    u += 0x7fffu + ((u >> 16) & 1u);
    return (unsigned short)(u >> 16);
}

static __device__ __forceinline__ void load16_lds(const void* gp, void* lp) {
    // 16B per lane, LDS dest = wave-uniform base + lane*16
    __builtin_amdgcn_global_load_lds(
        (const __attribute__((address_space(1))) unsigned int*)gp,
        (__attribute__((address_space(3))) unsigned int*)lp,
        16, 0, 0);
}

struct ushort4s { unsigned short x, y, z, w; };

// ---------------- prep: norms + diag dist + fp32->bf16 conversion ----------------
__global__ __launch_bounds__(256) void taw_prep_kernel(
        const float* __restrict__ a, const float* __restrict__ p,
        float* __restrict__ ws) {
    const int i = blockIdx.x;
    const int t = threadIdx.x;
    if (i == 0 && t == 0) {
        ws[1536] = 0.0f;
        ((unsigned int*)ws)[1537] = 0u;
        ((unsigned int*)ws)[1538] = 0u;
    }
    const float4* a4 = (const float4*)(a + (size_t)i * PD);
    const float4* p4 = (const float4*)(p + (size_t)i * PD);
    unsigned short* ah = (unsigned short*)((char*)ws + WS_AH_BYTES) + (size_t)i * PD;
    unsigned short* ph = (unsigned short*)((char*)ws + WS_PH_BYTES) + (size_t)i * PD;
    float sa = 0.f, sp = 0.f, dp = 0.f;
#pragma unroll
    for (int c = 0; c < 4; ++c) {
        const int e = c * 256 + t;      // float4 index
        float4 av = a4[e];
        float4 pv = p4[e];
        sa += av.x * av.x + av.y * av.y + av.z * av.z + av.w * av.w;
        sp += pv.x * pv.x + pv.y * pv.y + pv.z * pv.z + pv.w * pv.w;
        dp += av.x * pv.x + av.y * pv.y + av.z * pv.z + av.w * pv.w;
        ushort4s ab = {f2bf(av.x), f2bf(av.y), f2bf(av.z), f2bf(av.w)};
        ushort4s pb = {f2bf(pv.x), f2bf(pv.y), f2bf(pv.z), f2bf(pv.w)};
        *(ushort4s*)(ah + (size_t)e * 4) = ab;
        *(ushort4s*)(ph + (size_t)e * 4) = pb;
    }
#pragma unroll
    for (int off = 32; off > 0; off >>= 1) {
        sa += __shfl_down(sa, off, 64);
        sp += __shfl_down(sp, off, 64);
        dp += __shfl_down(dp, off, 64);
    }
    __shared__ float red[3][4];
    const int wave = t >> 6;
    if ((t & 63) == 0) { red[0][wave] = sa; red[1][wave] = sp; red[2][wave] = dp; }
    __syncthreads();
    if (t == 0) {
        sa = red[0][0] + red[0][1] + red[0][2] + red[0][3];
        sp = red[1][0] + red[1][1] + red[1][2] + red[1][3];
        dp = red[2][0] + red[2][1] + red[2][2] + red[2][3];
        float d2 = sa - 2.f * dp + sp;
        d2 = fmaxf(d2, 0.f);
        ws[i] = sa;
        ws[512 + i] = sp;
        ws[1024 + i] = (d2 == 0.f) ? 0.f : sqrtf(d2);
    }
}

// ---------------- bf16 MFMA split-K GEMM: 64x64 tile, Kchunk 512 ----------------
// grid (8, 8, KSZ), block 256 (4 waves; wave w -> 32x32 quadrant (w>>1, w&1)).
// Champion fragment geometry (R0-verified), now with a triple-buffered LDS
// pipeline: prefetch depth 2, counted s_waitcnt vmcnt(8) (4 global_load_lds
// per wave per stage; 2 stages stay in flight across barriers), raw s_barrier
// instead of __syncthreads full drains.
// LDS fragment order: lds[buf][A/B][group g=s2*4+rb][lane][8 bf16];
// group g holds rows rb*16+(lane&15), k = s2*32+(lane>>4)*8 of the BK=64 slab.
__global__ __launch_bounds__(256) void taw_mfma_kernel(float* __restrict__ ws) {
    __shared__ short lds[3][2][8][64][8];  // 48 KB triple buffer -> 2 blocks/CU
    const unsigned short* ah = (const unsigned short*)((const char*)ws + WS_AH_BYTES);
    const unsigned short* ph = (const unsigned short*)((const char*)ws + WS_PH_BYTES);
    const int t = threadIdx.x;
    const int lane = t & 63;
    const int w = t >> 6;
    const int wm = w >> 1, wn = w & 1;
    const int i0 = blockIdx.y * 64;
    const int j0 = blockIdx.x * 64;
    const int kz = blockIdx.z * KCHUNK;

    // Per-wave staging addresses: wave w stages groups 2w, 2w+1 of each tensor.
    const unsigned short* abase[2];
    const unsigned short* pbase[2];
#pragma unroll
    for (int q = 0; q < 2; ++q) {
        const int g = 2 * w + q;
        const int row = ((g & 3) << 4) + (lane & 15);
        const int kofs = ((g >> 2) << 5) + ((lane >> 4) << 3);
        abase[q] = ah + (size_t)(i0 + row) * PD + kz + kofs;
        pbase[q] = ph + (size_t)(j0 + row) * PD + kz + kofs;
    }

    auto STAGE = [&](int buf, int kb) {
#pragma unroll
        for (int q = 0; q < 2; ++q) {
            load16_lds(abase[q] + kb, &lds[buf][0][2 * w + q][0][0]);
            load16_lds(pbase[q] + kb, &lds[buf][1][2 * w + q][0][0]);
        }
    };

    floatx4 acc[2][2] = {{{0.f, 0.f, 0.f, 0.f}, {0.f, 0.f, 0.f, 0.f}},
                         {{0.f, 0.f, 0.f, 0.f}, {0.f, 0.f, 0.f, 0.f}}};

    STAGE(0, 0);
    STAGE(1, BK);
#pragma unroll
    for (int st = 0; st < NSTAGE; ++st) {
        const int b = st % 3;  // compile-time (full unroll)
        if (st + 2 < NSTAGE) {
            STAGE((st + 2) % 3, (st + 2) * BK);
            // stages st+1, st+2 (8 loads/wave) stay in flight; stage st landed
            asm volatile("s_waitcnt vmcnt(8)" ::: "memory");
        } else if (st + 1 < NSTAGE) {
            asm volatile("s_waitcnt vmcnt(4)" ::: "memory");
        } else {
            asm volatile("s_waitcnt vmcnt(0)" ::: "memory");
        }
        __builtin_amdgcn_s_barrier();   // all waves' stage-st loads landed
#pragma unroll
        for (int s2 = 0; s2 < 2; ++s2) {
            short8 af0 = *(const short8*)&lds[b][0][s2 * 4 + wm * 2 + 0][lane][0];
            short8 af1 = *(const short8*)&lds[b][0][s2 * 4 + wm * 2 + 1][lane][0];
            short8 bf0 = *(const short8*)&lds[b][1][s2 * 4 + wn * 2 + 0][lane][0];
            short8 bf1 = *(const short8*)&lds[b][1][s2 * 4 + wn * 2 + 1][lane][0];
            acc[0][0] = __builtin_amdgcn_mfma_f32_16x16x32_bf16(af0, bf0, acc[0][0], 0, 0, 0);
            acc[0][1] = __builtin_amdgcn_mfma_f32_16x16x32_bf16(af0, bf1, acc[0][1], 0, 0, 0);
            acc[1][0] = __builtin_amdgcn_mfma_f32_16x16x32_bf16(af1, bf0, acc[1][0], 0, 0, 0);
            acc[1][1] = __builtin_amdgcn_mfma_f32_16x16x32_bf16(af1, bf1, acc[1][1], 0, 0, 0);
        }
        asm volatile("s_waitcnt lgkmcnt(0)" ::: "memory");  // my ds_reads of buf b done
        __builtin_amdgcn_sched_barrier(0);  // rule 18: nothing hoists above the wait
        __builtin_amdgcn_s_barrier();       // everyone done -> buf b may be restaged
    }

    // Partials: C/D layout col=lane&15, row=(lane>>4)*4+reg [m89-verified]
    float* part = ws + WS_PART_FLOAT + (size_t)blockIdx.z * (PN * PN);
    const int jj = j0 + wn * 32 + (lane & 15);
    const int ib = i0 + wm * 32 + ((lane >> 4) << 2);
#pragma unroll
    for (int rm = 0; rm < 2; ++rm)
#pragma unroll
        for (int rn = 0; rn < 2; ++rn)
#pragma unroll
            for (int r = 0; r < 4; ++r)
                part[(size_t)(ib + rm * 16 + r) * PN + jj + rn * 16] = acc[rm][rn][r];
}

// ---------------- reduce partials + epilogue + ticketed finalize ----------------
__global__ __launch_bounds__(256) void taw_reduce_kernel(float* __restrict__ ws,
                                                         float* __restrict__ out) {
    const int g = blockIdx.x * 256 + threadIdx.x;  // 0..65535, one float4 each
    const float4* part4 = (const float4*)(ws + WS_PART_FLOAT);
    float4 dot = part4[g];
#pragma unroll
    for (int ks = 1; ks < KSZ; ++ks) {
        const float4 v = part4[((size_t)ks << 16) + g];
        dot.x += v.x; dot.y += v.y; dot.z += v.z; dot.w += v.w;
    }
    const int flat = g << 2;
    const int i = flat >> 9;
    const int j = flat & 511;
    const float sa = ws[i];
    const float dd = ws[1024 + i];
    const float4 sp4 = *(const float4*)(ws + 512 + j);
    const float dotr[4] = {dot.x, dot.y, dot.z, dot.w};
    const float spr[4] = {sp4.x, sp4.y, sp4.z, sp4.w};
    float lsum = 0.f;
    unsigned int lcnt = 0;
#pragma unroll
    for (int c = 0; c < 4; ++c) {
        const int jj = j + c;
        float d2 = sa - 2.f * dotr[c] + spr[c];
        d2 = fmaxf(d2, 0.f);
        const float dist = (d2 == 0.f) ? 0.f : sqrtf(d2);
        const float v = (i != jj) ? fmaxf(dd - dist, 0.f) : 0.f;
        lsum += v;
        lcnt += (v > 1e-16f) ? 1u : 0u;
    }
#pragma unroll
    for (int off = 32; off > 0; off >>= 1) {
        lsum += __shfl_down(lsum, off, 64);
        lcnt += __shfl_down(lcnt, off, 64);
    }
    __shared__ float rsum[4];
    __shared__ unsigned int rcnt[4];
    const int t = threadIdx.x;
    if ((t & 63) == 0) { rsum[t >> 6] = lsum; rcnt[t >> 6] = lcnt; }
    __syncthreads();
    if (t == 0) {
        atomicAdd(ws + 1536, rsum[0] + rsum[1] + rsum[2] + rsum[3]);
        atomicAdd(((unsigned int*)ws) + 1537, rcnt[0] + rcnt[1] + rcnt[2] + rcnt[3]);
        __threadfence();  // make this block's sums device-visible before ticket
        const unsigned int old = atomicAdd(((unsigned int*)ws) + 1538, 1u);
        if (old == 255u) {  // last of 256 blocks: all atomics visible
            const float s = atomicAdd(ws + 1536, 0.f);          // coherent read
            const unsigned int c = atomicAdd(((unsigned int*)ws) + 1537, 0u);
            out[0] = (float)((double)s / ((double)c + 1e-16));
        }
    }
}

// ---------------- finalize (fallback path only) ----------------
__global__ void taw_finalize_kernel(const float* __restrict__ ws,
                                    float* __restrict__ out) {
    const double s = (double)ws[1536];
    const double c = (double)(((const unsigned int*)ws)[1537]);
    out[0] = (float)(s / (c + 1e-16));
}

// ---------------- fallback single-pass fp32 GEMM (Round-0/1 proven path) ----------------
__global__ __launch_bounds__(256) void taw_gemm_loss_kernel(
        const float* __restrict__ A, const float* __restrict__ P,
        float* __restrict__ ws) {
    __shared__ float as[32][34];
    __shared__ float bs[32][34];
    const int tx = threadIdx.x;
    const int ty = threadIdx.y;
    const int t = ty * 16 + tx;
    const int i0 = blockIdx.y * 32;
    const int j0 = blockIdx.x * 32;
    const int sr = t >> 3;
    const int sk = (t & 7) * 4;
    const float* aptr = A + (size_t)(i0 + sr) * PD + sk;
    const float* pptr = P + (size_t)(j0 + sr) * PD + sk;
    float c00 = 0.f, c01 = 0.f, c10 = 0.f, c11 = 0.f;
    for (int k0 = 0; k0 < PD; k0 += 32) {
        float4 av = *(const float4*)(aptr + k0);
        float4 pv = *(const float4*)(pptr + k0);
        __syncthreads();
        as[sk + 0][sr] = av.x; as[sk + 1][sr] = av.y;
        as[sk + 2][sr] = av.z; as[sk + 3][sr] = av.w;
        bs[sk + 0][sr] = pv.x; bs[sk + 1][sr] = pv.y;
        bs[sk + 2][sr] = pv.z; bs[sk + 3][sr] = pv.w;
        __syncthreads();
#pragma unroll
        for (int kk = 0; kk < 32; ++kk) {
            const float2 a2 = *(const float2*)&as[kk][2 * ty];
            const float2 b2 = *(const float2*)&bs[kk][2 * tx];
            c00 = fmaf(a2.x, b2.x, c00);
            c01 = fmaf(a2.x, b2.y, c01);
            c10 = fmaf(a2.y, b2.x, c10);
            c11 = fmaf(a2.y, b2.y, c11);
        }
    }
    const float* sq_a = ws;
    const float* sq_p = ws + 512;
    const float* ddg  = ws + 1024;
    const int i = i0 + 2 * ty;
    const int j = j0 + 2 * tx;
    float cvals[2][2] = {{c00, c01}, {c10, c11}};
    float lsum = 0.f;
    unsigned int lcnt = 0;
#pragma unroll
    for (int dr = 0; dr < 2; ++dr)
#pragma unroll
        for (int dc = 0; dc < 2; ++dc) {
            const int ii = i + dr, jj = j + dc;
            float d2 = sq_a[ii] - 2.f * cvals[dr][dc] + sq_p[jj];
            d2 = fmaxf(d2, 0.f);
            const float dist = (d2 == 0.f) ? 0.f : sqrtf(d2);
            const float v = (ii != jj) ? fmaxf(ddg[ii] - dist, 0.f) : 0.f;
            lsum += v;
            lcnt += (v > 1e-16f) ? 1u : 0u;
        }
#pragma unroll
    for (int off = 32; off > 0; off >>= 1) {
        lsum += __shfl_down(lsum, off, 64);
        lcnt += __shfl_down(lcnt, off, 64);
    }
    __shared__ float rsum[4];
    __shared__ unsigned int rcnt[4];
    if ((t & 63) == 0) { rsum[t >> 6] = lsum; rcnt[t >> 6] = lcnt; }
    __syncthreads();
    if (t == 0) {
        atomicAdd(ws + 1536, rsum[0] + rsum[1] + rsum[2] + rsum[3]);
        atomicAdd(((unsigned int*)ws) + 1537, rcnt[0] + rcnt[1] + rcnt[2] + rcnt[3]);
    }
}

extern "C" void kernel_launch(void* const* d_in, const int* in_sizes, int n_in,
                              void* d_out, int out_size, void* d_ws, size_t ws_size,
                              hipStream_t stream) {
    (void)in_sizes; (void)n_in; (void)out_size;
    const float* a = (const float*)d_in[0];
    const float* p = (const float*)d_in[1];
    float* out = (float*)d_out;
    float* ws = (float*)d_ws;

    taw_prep_kernel<<<PN, 256, 0, stream>>>(a, p, ws);
    if (ws_size >= WS_NEED_BF16) {
        taw_mfma_kernel<<<dim3(8, 8, KSZ), 256, 0, stream>>>(ws);
        taw_reduce_kernel<<<256, 256, 0, stream>>>(ws, out);
    } else {
        taw_gemm_loss_kernel<<<dim3(16, 16), dim3(16, 16), 0, stream>>>(a, p, ws);
        taw_finalize_kernel<<<1, 1, 0, stream>>>(ws, out);
    }
}

// Round 5
// 91.198 us; speedup vs baseline: 1.1707x; 1.0118x over previous
//
#include <hip/hip_runtime.h>
#include <math.h>

// Problem constants (from reference: N=512, D=4096, fp32).
#define PN 512
#define PD 4096

// bf16 MFMA split-K config (champion geometry, R0-verified at 87.7us)
#define KSZ 8
#define KCHUNK (PD / KSZ)     // 512
#define BK 64                 // K per LDS stage
#define NSTAGE (KCHUNK / BK)  // 8

// ws layout (bytes):
//   [0,2048)    sa (512 f32)        float idx 0
//   [2048,4096) sp                  float idx 512
//   [4096,6144) dd (diag dist)      float idx 1024
//   [6144]      sum (f32 atomic)    float idx 1536
//   [6148]      cnt (u32 atomic)    idx 1537
//   [6152]      done (u32 ticket)   idx 1538
//   [8192, +4MB)        ah bf16 [512][4096]
//   [8192+4MB, +8MB)    ph bf16 [512][4096]
//   [8192+8MB, +8MB)    split-K partials f32 [KSZ][512][512]
#define WS_AH_BYTES 8192
#define WS_PH_BYTES (8192 + 4194304)
#define WS_PART_FLOAT 2099200                 // (8192 + 2*4194304)/4
#define WS_NEED_BF16 ((size_t)(8192 + 2 * 4194304 + (size_t)KSZ * PN * PN * 4))

typedef __attribute__((ext_vector_type(8))) short short8;
typedef __attribute__((ext_vector_type(4))) float floatx4;

static __device__ __forceinline__ unsigned short f2bf(float x) {
    // round-to-nearest-even fp32 -> bf16 (inputs are finite normals)
    unsigned int u = __float_as_uint(x);
    u += 0x7fffu + ((u >> 16) & 1u);
    return (unsigned short)(u >> 16);
}

static __device__ __forceinline__ void load16_lds(const void* gp, void* lp) {
    // 16B per lane, LDS dest = wave-uniform base + lane*16
    __builtin_amdgcn_global_load_lds(
        (const __attribute__((address_space(1))) unsigned int*)gp,
        (__attribute__((address_space(3))) unsigned int*)lp,
        16, 0, 0);
}

struct ushort4s { unsigned short x, y, z, w; };

// ---------------- prep: norms + diag dist + fp32->bf16 conversion ----------------
__global__ __launch_bounds__(256) void taw_prep_kernel(
        const float* __restrict__ a, const float* __restrict__ p,
        float* __restrict__ ws) {
    const int i = blockIdx.x;
    const int t = threadIdx.x;
    if (i == 0 && t == 0) {
        ws[1536] = 0.0f;
        ((unsigned int*)ws)[1537] = 0u;
        ((unsigned int*)ws)[1538] = 0u;
    }
    const float4* a4 = (const float4*)(a + (size_t)i * PD);
    const float4* p4 = (const float4*)(p + (size_t)i * PD);
    unsigned short* ah = (unsigned short*)((char*)ws + WS_AH_BYTES) + (size_t)i * PD;
    unsigned short* ph = (unsigned short*)((char*)ws + WS_PH_BYTES) + (size_t)i * PD;
    float sa = 0.f, sp = 0.f, dp = 0.f;
#pragma unroll
    for (int c = 0; c < 4; ++c) {
        const int e = c * 256 + t;      // float4 index
        float4 av = a4[e];
        float4 pv = p4[e];
        sa += av.x * av.x + av.y * av.y + av.z * av.z + av.w * av.w;
        sp += pv.x * pv.x + pv.y * pv.y + pv.z * pv.z + pv.w * pv.w;
        dp += av.x * pv.x + av.y * pv.y + av.z * pv.z + av.w * pv.w;
        ushort4s ab = {f2bf(av.x), f2bf(av.y), f2bf(av.z), f2bf(av.w)};
        ushort4s pb = {f2bf(pv.x), f2bf(pv.y), f2bf(pv.z), f2bf(pv.w)};
        *(ushort4s*)(ah + (size_t)e * 4) = ab;
        *(ushort4s*)(ph + (size_t)e * 4) = pb;
    }
#pragma unroll
    for (int off = 32; off > 0; off >>= 1) {
        sa += __shfl_down(sa, off, 64);
        sp += __shfl_down(sp, off, 64);
        dp += __shfl_down(dp, off, 64);
    }
    __shared__ float red[3][4];
    const int wave = t >> 6;
    if ((t & 63) == 0) { red[0][wave] = sa; red[1][wave] = sp; red[2][wave] = dp; }
    __syncthreads();
    if (t == 0) {
        sa = red[0][0] + red[0][1] + red[0][2] + red[0][3];
        sp = red[1][0] + red[1][1] + red[1][2] + red[1][3];
        dp = red[2][0] + red[2][1] + red[2][2] + red[2][3];
        float d2 = sa - 2.f * dp + sp;
        d2 = fmaxf(d2, 0.f);
        ws[i] = sa;
        ws[512 + i] = sp;
        ws[1024 + i] = (d2 == 0.f) ? 0.f : sqrtf(d2);
    }
}

// ---------------- bf16 MFMA split-K GEMM: 64x64 tile, Kchunk 512 ----------------
// grid (8, 8, KSZ), block 256 (4 waves; wave w -> 32x32 quadrant (w>>1, w&1)).
// EXACT champion body (R0, 87.7us): serial staging + __syncthreads drains.
// At 2 blocks/CU, cross-block TLP hides the staging latency; explicit
// pipelining regressed (R4: 92.3) -- do not re-add.
// LDS in fragment order: lds[A/B][group g=s*4+rb][lane][8 bf16];
// group g holds rows rb*16+(lane&15), k-chunk s*4+(lane>>4) (8 bf16 each).
__global__ __launch_bounds__(256) void taw_mfma_kernel(float* __restrict__ ws) {
    __shared__ short lds[2][8][64][8];  // 16 KB
    const unsigned short* ah = (const unsigned short*)((const char*)ws + WS_AH_BYTES);
    const unsigned short* ph = (const unsigned short*)((const char*)ws + WS_PH_BYTES);
    const int t = threadIdx.x;
    const int lane = t & 63;
    const int w = t >> 6;
    const int wm = w >> 1, wn = w & 1;
    const int i0 = blockIdx.y * 64;
    const int j0 = blockIdx.x * 64;
    const int kz = blockIdx.z * KCHUNK;

    floatx4 acc[2][2] = {{{0.f, 0.f, 0.f, 0.f}, {0.f, 0.f, 0.f, 0.f}},
                         {{0.f, 0.f, 0.f, 0.f}, {0.f, 0.f, 0.f, 0.f}}};

    for (int st = 0; st < NSTAGE; ++st) {
        const int kb = kz + st * BK;
        __syncthreads();  // all ds_reads of previous stage done
#pragma unroll
        for (int q = 0; q < 2; ++q) {
            const int g = 2 * w + q;                       // wave w stages groups 2w, 2w+1
            const int row = ((g & 3) << 4) + (lane & 15);
            const int kk = kb + ((((g >> 2) << 2) + (lane >> 4)) << 3);
            load16_lds(ah + (size_t)(i0 + row) * PD + kk, &lds[0][g][0][0]);
            load16_lds(ph + (size_t)(j0 + row) * PD + kk, &lds[1][g][0][0]);
        }
        __syncthreads();  // drains vmcnt(0): staged data visible
#pragma unroll
        for (int s2 = 0; s2 < 2; ++s2) {
            short8 af0 = *(const short8*)&lds[0][s2 * 4 + wm * 2 + 0][lane][0];
            short8 af1 = *(const short8*)&lds[0][s2 * 4 + wm * 2 + 1][lane][0];
            short8 bf0 = *(const short8*)&lds[1][s2 * 4 + wn * 2 + 0][lane][0];
            short8 bf1 = *(const short8*)&lds[1][s2 * 4 + wn * 2 + 1][lane][0];
            acc[0][0] = __builtin_amdgcn_mfma_f32_16x16x32_bf16(af0, bf0, acc[0][0], 0, 0, 0);
            acc[0][1] = __builtin_amdgcn_mfma_f32_16x16x32_bf16(af0, bf1, acc[0][1], 0, 0, 0);
            acc[1][0] = __builtin_amdgcn_mfma_f32_16x16x32_bf16(af1, bf0, acc[1][0], 0, 0, 0);
            acc[1][1] = __builtin_amdgcn_mfma_f32_16x16x32_bf16(af1, bf1, acc[1][1], 0, 0, 0);
        }
    }

    // Partials: C/D layout col=lane&15, row=(lane>>4)*4+reg [m89-verified]
    float* part = ws + WS_PART_FLOAT + (size_t)blockIdx.z * (PN * PN);
    const int jj = j0 + wn * 32 + (lane & 15);
    const int ib = i0 + wm * 32 + ((lane >> 4) << 2);
#pragma unroll
    for (int rm = 0; rm < 2; ++rm)
#pragma unroll
        for (int rn = 0; rn < 2; ++rn)
#pragma unroll
            for (int r = 0; r < 4; ++r)
                part[(size_t)(ib + rm * 16 + r) * PN + jj + rn * 16] = acc[rm][rn][r];
}

// ---------------- reduce partials + epilogue + ticketed finalize ----------------
// Only delta vs champion: the finalize kernel is merged in via a device-scope
// ticket (atomics + __threadfence; winner re-reads sums via atomic adds of 0).
__global__ __launch_bounds__(256) void taw_reduce_kernel(float* __restrict__ ws,
                                                         float* __restrict__ out) {
    const int g = blockIdx.x * 256 + threadIdx.x;  // 0..65535, one float4 each
    const float4* part4 = (const float4*)(ws + WS_PART_FLOAT);
    float4 dot = part4[g];
#pragma unroll
    for (int ks = 1; ks < KSZ; ++ks) {
        const float4 v = part4[((size_t)ks << 16) + g];
        dot.x += v.x; dot.y += v.y; dot.z += v.z; dot.w += v.w;
    }
    const int flat = g << 2;
    const int i = flat >> 9;
    const int j = flat & 511;
    const float sa = ws[i];
    const float dd = ws[1024 + i];
    const float4 sp4 = *(const float4*)(ws + 512 + j);
    const float dotr[4] = {dot.x, dot.y, dot.z, dot.w};
    const float spr[4] = {sp4.x, sp4.y, sp4.z, sp4.w};
    float lsum = 0.f;
    unsigned int lcnt = 0;
#pragma unroll
    for (int c = 0; c < 4; ++c) {
        const int jj = j + c;
        float d2 = sa - 2.f * dotr[c] + spr[c];
        d2 = fmaxf(d2, 0.f);
        const float dist = (d2 == 0.f) ? 0.f : sqrtf(d2);
        const float v = (i != jj) ? fmaxf(dd - dist, 0.f) : 0.f;
        lsum += v;
        lcnt += (v > 1e-16f) ? 1u : 0u;
    }
#pragma unroll
    for (int off = 32; off > 0; off >>= 1) {
        lsum += __shfl_down(lsum, off, 64);
        lcnt += __shfl_down(lcnt, off, 64);
    }
    __shared__ float rsum[4];
    __shared__ unsigned int rcnt[4];
    const int t = threadIdx.x;
    if ((t & 63) == 0) { rsum[t >> 6] = lsum; rcnt[t >> 6] = lcnt; }
    __syncthreads();
    if (t == 0) {
        atomicAdd(ws + 1536, rsum[0] + rsum[1] + rsum[2] + rsum[3]);
        atomicAdd(((unsigned int*)ws) + 1537, rcnt[0] + rcnt[1] + rcnt[2] + rcnt[3]);
        __threadfence();  // make this block's sums device-visible before ticket
        const unsigned int old = atomicAdd(((unsigned int*)ws) + 1538, 1u);
        if (old == 255u) {  // last of 256 blocks: all atomics visible
            const float s = atomicAdd(ws + 1536, 0.f);          // coherent read
            const unsigned int c = atomicAdd(((unsigned int*)ws) + 1537, 0u);
            out[0] = (float)((double)s / ((double)c + 1e-16));
        }
    }
}

// ---------------- finalize (fallback path only) ----------------
__global__ void taw_finalize_kernel(const float* __restrict__ ws,
                                    float* __restrict__ out) {
    const double s = (double)ws[1536];
    const double c = (double)(((const unsigned int*)ws)[1537]);
    out[0] = (float)(s / (c + 1e-16));
}

// ---------------- fallback single-pass fp32 GEMM (Round-0/1 proven path) ----------------
__global__ __launch_bounds__(256) void taw_gemm_loss_kernel(
        const float* __restrict__ A, const float* __restrict__ P,
        float* __restrict__ ws) {
    __shared__ float as[32][34];
    __shared__ float bs[32][34];
    const int tx = threadIdx.x;
    const int ty = threadIdx.y;
    const int t = ty * 16 + tx;
    const int i0 = blockIdx.y * 32;
    const int j0 = blockIdx.x * 32;
    const int sr = t >> 3;
    const int sk = (t & 7) * 4;
    const float* aptr = A + (size_t)(i0 + sr) * PD + sk;
    const float* pptr = P + (size_t)(j0 + sr) * PD + sk;
    float c00 = 0.f, c01 = 0.f, c10 = 0.f, c11 = 0.f;
    for (int k0 = 0; k0 < PD; k0 += 32) {
        float4 av = *(const float4*)(aptr + k0);
        float4 pv = *(const float4*)(pptr + k0);
        __syncthreads();
        as[sk + 0][sr] = av.x; as[sk + 1][sr] = av.y;
        as[sk + 2][sr] = av.z; as[sk + 3][sr] = av.w;
        bs[sk + 0][sr] = pv.x; bs[sk + 1][sr] = pv.y;
        bs[sk + 2][sr] = pv.z; bs[sk + 3][sr] = pv.w;
        __syncthreads();
#pragma unroll
        for (int kk = 0; kk < 32; ++kk) {
            const float2 a2 = *(const float2*)&as[kk][2 * ty];
            const float2 b2 = *(const float2*)&bs[kk][2 * tx];
            c00 = fmaf(a2.x, b2.x, c00);
            c01 = fmaf(a2.x, b2.y, c01);
            c10 = fmaf(a2.y, b2.x, c10);
            c11 = fmaf(a2.y, b2.y, c11);
        }
    }
    const float* sq_a = ws;
    const float* sq_p = ws + 512;
    const float* ddg  = ws + 1024;
    const int i = i0 + 2 * ty;
    const int j = j0 + 2 * tx;
    float cvals[2][2] = {{c00, c01}, {c10, c11}};
    float lsum = 0.f;
    unsigned int lcnt = 0;
#pragma unroll
    for (int dr = 0; dr < 2; ++dr)
#pragma unroll
        for (int dc = 0; dc < 2; ++dc) {
            const int ii = i + dr, jj = j + dc;
            float d2 = sq_a[ii] - 2.f * cvals[dr][dc] + sq_p[jj];
            d2 = fmaxf(d2, 0.f);
            const float dist = (d2 == 0.f) ? 0.f : sqrtf(d2);
            const float v = (ii != jj) ? fmaxf(ddg[ii] - dist, 0.f) : 0.f;
            lsum += v;
            lcnt += (v > 1e-16f) ? 1u : 0u;
        }
#pragma unroll
    for (int off = 32; off > 0; off >>= 1) {
        lsum += __shfl_down(lsum, off, 64);
        lcnt += __shfl_down(lcnt, off, 64);
    }
    __shared__ float rsum[4];
    __shared__ unsigned int rcnt[4];
    if ((t & 63) == 0) { rsum[t >> 6] = lsum; rcnt[t >> 6] = lcnt; }
    __syncthreads();
    if (t == 0) {
        atomicAdd(ws + 1536, rsum[0] + rsum[1] + rsum[2] + rsum[3]);
        atomicAdd(((unsigned int*)ws) + 1537, rcnt[0] + rcnt[1] + rcnt[2] + rcnt[3]);
    }
}

extern "C" void kernel_launch(void* const* d_in, const int* in_sizes, int n_in,
                              void* d_out, int out_size, void* d_ws, size_t ws_size,
                              hipStream_t stream) {
    (void)in_sizes; (void)n_in; (void)out_size;
    const float* a = (const float*)d_in[0];
    const float* p = (const float*)d_in[1];
    float* out = (float*)d_out;
    float* ws = (float*)d_ws;

    taw_prep_kernel<<<PN, 256, 0, stream>>>(a, p, ws);
    if (ws_size >= WS_NEED_BF16) {
        taw_mfma_kernel<<<dim3(8, 8, KSZ), 256, 0, stream>>>(ws);
        taw_reduce_kernel<<<256, 256, 0, stream>>>(ws, out);
    } else {
        taw_gemm_loss_kernel<<<dim3(16, 16), dim3(16, 16), 0, stream>>>(a, p, ws);
        taw_finalize_kernel<<<1, 1, 0, stream>>>(ws, out);
    }
}